// Round 1
// baseline (309.547 us; speedup 1.0000x reference)
//
#include <hip/hip_runtime.h>

// DAWN_14886356647950: fused gated sparse read-write (B=2,S=1024,D=1024,N=8192,NC=8)
// Pipeline: prep(bf16 casts + emb row-norm + w_write transpose) -> stats GEMM ->
// tau -> gates (2 fused NT-GEMMs + gating + A=bf16(eg*xr)) -> scales -> out GEMM
// (per-chunk bf16 rounding) . All bf16 rounding points mirror JAX semantics (RTNE,
// f32 accumulation inside dots, bf16 result rounding).

#define MDIM 2048
#define DDIM 1024
#define NDIM 8192

typedef __attribute__((ext_vector_type(8))) __bf16 bf16x8;
typedef __attribute__((ext_vector_type(4))) float f32x4;

static __device__ __forceinline__ unsigned short f2b(float f) {
  unsigned u = __float_as_uint(f);
  u = (u + 0x7FFFu + ((u >> 16) & 1u)) >> 16;  // RTNE
  return (unsigned short)u;
}
static __device__ __forceinline__ float b2f(unsigned short s) {
  return __uint_as_float(((unsigned)s) << 16);
}

// Stage a TROWS x 64 bf16 tile (row-major, row stride ld elems) into linear LDS.
// LDS chunk layout matches global_load_lds's base + lane*16B linear write.
template <int TROWS>
static __device__ __forceinline__ void stage_tile(const unsigned short* __restrict__ src,
                                                  int row0, int k0, int ld,
                                                  unsigned short* lds, int wave, int lane) {
  const int rsub = lane >> 3;         // 8 rows per 1KB chunk
  const int csub = (lane & 7) << 3;   // 8 bf16 (16B) per lane
#pragma unroll
  for (int q = 0; q < TROWS / 32; ++q) {
    const int p = q * 4 + wave;  // wave-uniform chunk id
    const unsigned short* g =
        src + (size_t)(row0 + p * 8 + rsub) * (size_t)ld + (size_t)(k0 + csub);
    __builtin_amdgcn_global_load_lds(
        (const __attribute__((address_space(1))) unsigned int*)(const void*)g,
        (__attribute__((address_space(3))) unsigned int*)(void*)(lds + p * 512),
        16, 0, 0);
  }
}

// NT-GEMM: acc[4][4] (+=) asrc[m0..+128][K] * bsrc[n0..+128][K]^T, BK=64, 4 waves 2x2.
static __device__ __forceinline__ void gemm_128_128(const unsigned short* __restrict__ asrc,
                                                    const unsigned short* __restrict__ bsrc,
                                                    int m0, int n0, int K, int lda, int ldb,
                                                    unsigned short* a_sm, unsigned short* b_sm,
                                                    f32x4 (&acc)[4][4], int wave, int lane,
                                                    int wr, int wc) {
  const int arow = lane & 15;
  const int kcol = (lane >> 4) << 3;
  for (int k0 = 0; k0 < K; k0 += 64) {
    stage_tile<128>(asrc, m0, k0, lda, a_sm, wave, lane);
    stage_tile<128>(bsrc, n0, k0, ldb, b_sm, wave, lane);
    asm volatile("s_waitcnt vmcnt(0)" ::: "memory");
    __syncthreads();
#pragma unroll
    for (int ks = 0; ks < 2; ++ks) {
      bf16x8 af[4], bfr[4];
#pragma unroll
      for (int m = 0; m < 4; ++m)
        af[m] = *(const bf16x8*)&a_sm[(wr * 64 + m * 16 + arow) * 64 + ks * 32 + kcol];
#pragma unroll
      for (int n = 0; n < 4; ++n)
        bfr[n] = *(const bf16x8*)&b_sm[(wc * 64 + n * 16 + arow) * 64 + ks * 32 + kcol];
#pragma unroll
      for (int m = 0; m < 4; ++m)
#pragma unroll
        for (int n = 0; n < 4; ++n)
          acc[m][n] = __builtin_amdgcn_mfma_f32_16x16x32_bf16(af[m], bfr[n], acc[m][n], 0, 0, 0);
    }
    __syncthreads();
  }
}

// ---------- prep kernels ----------

__global__ __launch_bounds__(256) void k_norm(const float* __restrict__ emb,
                                              unsigned short* __restrict__ eb) {
  const int n = blockIdx.x, t = threadIdx.x;
  const float4 v = ((const float4*)(emb + (size_t)n * 1024))[t];
  float ss = v.x * v.x + v.y * v.y + v.z * v.z + v.w * v.w;
#pragma unroll
  for (int off = 1; off < 64; off <<= 1) ss += __shfl_xor(ss, off, 64);
  __shared__ float wsum[4];
  if ((t & 63) == 0) wsum[t >> 6] = ss;
  __syncthreads();
  const float tot = wsum[0] + wsum[1] + wsum[2] + wsum[3];
  const float denom = sqrtf(tot) + 1e-8f;
  ushort4 o;
  o.x = f2b(v.x / denom);
  o.y = f2b(v.y / denom);
  o.z = f2b(v.z / denom);
  o.w = f2b(v.w / denom);
  ((ushort4*)(eb + (size_t)n * 1024))[t] = o;
}

__global__ __launch_bounds__(256) void k_cast(const float* __restrict__ in,
                                              unsigned short* __restrict__ out, int n4) {
  const int i = blockIdx.x * 256 + threadIdx.x;
  if (i >= n4) return;
  const float4 v = ((const float4*)in)[i];
  ushort4 o;
  o.x = f2b(v.x);
  o.y = f2b(v.y);
  o.z = f2b(v.z);
  o.w = f2b(v.w);
  ((ushort4*)out)[i] = o;
}

// w_write [N][D] f32 -> wbT [D][N] bf16 (64x64 tiles)
__global__ __launch_bounds__(256) void k_twt(const float* __restrict__ w,
                                             unsigned short* __restrict__ wbT) {
  __shared__ float tsm[64][65];
  const int nb = blockIdx.x, db = blockIdx.y, t = threadIdx.x;
  const int r = t >> 2, c4 = (t & 3) * 16;
#pragma unroll
  for (int j = 0; j < 4; ++j) {
    const float4 v = *(const float4*)&w[(size_t)(nb * 64 + r) * 1024 + db * 64 + c4 + 4 * j];
    tsm[r][c4 + 4 * j + 0] = v.x;
    tsm[r][c4 + 4 * j + 1] = v.y;
    tsm[r][c4 + 4 * j + 2] = v.z;
    tsm[r][c4 + 4 * j + 3] = v.w;
  }
  __syncthreads();
  const int dr = t >> 2, nc0 = (t & 3) * 16;
  unsigned pk[8];
#pragma unroll
  for (int j = 0; j < 8; ++j) {
    const unsigned lo = f2b(tsm[nc0 + 2 * j][dr]);
    const unsigned hi = f2b(tsm[nc0 + 2 * j + 1][dr]);
    pk[j] = lo | (hi << 16);
  }
  uint4* dst = (uint4*)(wbT + (size_t)(db * 64 + dr) * 8192 + nb * 64 + nc0);
  uint4 w0, w1;
  w0.x = pk[0]; w0.y = pk[1]; w0.z = pk[2]; w0.w = pk[3];
  w1.x = pk[4]; w1.y = pk[5]; w1.z = pk[6]; w1.w = pk[7];
  dst[0] = w0;
  dst[1] = w1;
}

// ---------- stats (chunk-0 sc sums) ----------

__global__ __launch_bounds__(256, 2) void k_stats(const unsigned short* __restrict__ hb,
                                                  const unsigned short* __restrict__ eb,
                                                  float* __restrict__ stat_s,
                                                  float* __restrict__ stat_q) {
  __shared__ unsigned short a_sm[128 * 64];
  __shared__ unsigned short b_sm[128 * 64];
  __shared__ float red_s[2][128];
  __shared__ float red_q[2][128];
  const int t = threadIdx.x;
  const int wave = t >> 6, lane = t & 63;
  const int wr = wave >> 1, wc = wave & 1;
  const int m0 = blockIdx.x * 128, n0 = blockIdx.y * 128;
  f32x4 acc[4][4];
#pragma unroll
  for (int m = 0; m < 4; ++m)
#pragma unroll
    for (int n = 0; n < 4; ++n) acc[m][n] = (f32x4)0.0f;
  gemm_128_128(hb, eb, m0, n0, 1024, 1024, 1024, a_sm, b_sm, acc, wave, lane, wr, wc);

  float s_r[4][4], q_r[4][4];
#pragma unroll
  for (int m = 0; m < 4; ++m)
#pragma unroll
    for (int i = 0; i < 4; ++i) { s_r[m][i] = 0.f; q_r[m][i] = 0.f; }
#pragma unroll
  for (int m = 0; m < 4; ++m)
#pragma unroll
    for (int n = 0; n < 4; ++n)
#pragma unroll
      for (int i = 0; i < 4; ++i) {
        const float scf = b2f(f2b(acc[m][n][i]));  // sc rounded to bf16
        s_r[m][i] += scf;
        q_r[m][i] += b2f(f2b(scf * scf));          // bf16 square
      }
#pragma unroll
  for (int m = 0; m < 4; ++m)
#pragma unroll
    for (int i = 0; i < 4; ++i) {
      float s = s_r[m][i], q = q_r[m][i];
      for (int off = 1; off < 16; off <<= 1) {
        s += __shfl_xor(s, off, 64);
        q += __shfl_xor(q, off, 64);
      }
      if ((lane & 15) == 0) {
        const int rloc = wr * 64 + m * 16 + (lane >> 4) * 4 + i;
        red_s[wc][rloc] = s;
        red_q[wc][rloc] = q;
      }
    }
  __syncthreads();
  if (t < 128) {
    stat_s[(size_t)(m0 + t) * 8 + blockIdx.y] = red_s[0][t] + red_s[1][t];
    stat_q[(size_t)(m0 + t) * 8 + blockIdx.y] = red_q[0][t] + red_q[1][t];
  }
}

__global__ void k_tau(const float* __restrict__ stat_s, const float* __restrict__ stat_q,
                      const float* __restrict__ tau_off, float* __restrict__ tau) {
  const int r = blockIdx.x * 256 + threadIdx.x;
  if (r >= MDIM) return;
  float S = 0.f, Q = 0.f;
#pragma unroll
  for (int j = 0; j < 8; ++j) {
    S += stat_s[(size_t)r * 8 + j];
    Q += stat_q[(size_t)r * 8 + j];
  }
  const float s_sum = S * 8.0f;
  const float sq_sum = Q * 8.0f;
  const float mean = s_sum * (1.0f / 8192.0f);
  const float var = __fsub_rn(sq_sum * (1.0f / 8192.0f), __fmul_rn(mean, mean));
  const float sd = __fadd_rn(__fsqrt_rn(var), 1e-8f);
  const float tv = __fadd_rn(mean, __fmul_rn(tau_off[r], sd));
  tau[r] = b2f(f2b(tv));  // store tau_bf as f32 value
}

// ---------- gates: sc GEMM + gating + xr GEMM + A store + es/em partials ----------

__global__ __launch_bounds__(256, 2) void k_gates(const unsigned short* __restrict__ hb,
                                                  const unsigned short* __restrict__ eb,
                                                  const unsigned short* __restrict__ xb,
                                                  const unsigned short* __restrict__ rb,
                                                  const float* __restrict__ tau,
                                                  unsigned short* __restrict__ A,
                                                  float* __restrict__ es_part,
                                                  float* __restrict__ em_part) {
  __shared__ unsigned short a_sm[128 * 64];
  __shared__ unsigned short b_sm[128 * 64];
  __shared__ float red_es[2][128];
  __shared__ float red_em[2][128];
  __shared__ float tau_sm[128];
  const int t = threadIdx.x;
  const int wave = t >> 6, lane = t & 63;
  const int wr = wave >> 1, wc = wave & 1;
  const int m0 = blockIdx.x * 128, n0 = blockIdx.y * 128;
  if (t < 128) tau_sm[t] = tau[m0 + t];

  f32x4 acc[4][4];
#pragma unroll
  for (int m = 0; m < 4; ++m)
#pragma unroll
    for (int n = 0; n < 4; ++n) acc[m][n] = (f32x4)0.0f;
  gemm_128_128(hb, eb, m0, n0, 1024, 1024, 1024, a_sm, b_sm, acc, wave, lane, wr, wc);

  unsigned eg_p[4][4][2];
  float es_r[4][4], em_r[4][4];
#pragma unroll
  for (int m = 0; m < 4; ++m)
#pragma unroll
    for (int i = 0; i < 4; ++i) { es_r[m][i] = 0.f; em_r[m][i] = 0.f; }

#pragma unroll
  for (int m = 0; m < 4; ++m) {
#pragma unroll
    for (int n = 0; n < 4; ++n) {
      unsigned p0 = 0, p1 = 0;
#pragma unroll
      for (int i = 0; i < 4; ++i) {
        const int rloc = wr * 64 + m * 16 + (lane >> 4) * 4 + i;
        const float taub = tau_sm[rloc];
        const float scf = b2f(f2b(acc[m][n][i]));          // sc bf16
        const float rawf = b2f(f2b(scf - taub));           // bf16 subtract
        float gcf;
        if (rawf > 0.f)
          gcf = fminf(rawf, 10.0f);                        // clip upper (bf16 exact)
        else
          gcf = b2f(f2b(1e-6f * expf(fmaxf(rawf, -10.0f))));
        const float egf = expf(gcf) - 1.0f;
        const unsigned short egu = f2b(egf);               // eg bf16
        const float ef = b2f(egu);
        es_r[m][i] += ef;
        em_r[m][i] = fmaxf(em_r[m][i], ef);
        if (i < 2) p0 |= ((unsigned)egu) << (16 * i);
        else       p1 |= ((unsigned)egu) << (16 * (i - 2));
      }
      eg_p[m][n][0] = p0;
      eg_p[m][n][1] = p1;
    }
  }

#pragma unroll
  for (int m = 0; m < 4; ++m)
#pragma unroll
    for (int i = 0; i < 4; ++i) {
      float s = es_r[m][i], e = em_r[m][i];
      for (int off = 1; off < 16; off <<= 1) {
        s += __shfl_xor(s, off, 64);
        e = fmaxf(e, __shfl_xor(e, off, 64));
      }
      if ((lane & 15) == 0) {
        const int rloc = wr * 64 + m * 16 + (lane >> 4) * 4 + i;
        red_es[wc][rloc] = s;
        red_em[wc][rloc] = e;
      }
    }
  __syncthreads();
  if (t < 128) {
    es_part[(size_t)(m0 + t) * 64 + blockIdx.y] = red_es[0][t] + red_es[1][t];
    em_part[(size_t)(m0 + t) * 64 + blockIdx.y] = fmaxf(red_em[0][t], red_em[1][t]);
  }

  // xr GEMM
#pragma unroll
  for (int m = 0; m < 4; ++m)
#pragma unroll
    for (int n = 0; n < 4; ++n) acc[m][n] = (f32x4)0.0f;
  gemm_128_128(xb, rb, m0, n0, 1024, 1024, 1024, a_sm, b_sm, acc, wave, lane, wr, wc);

#pragma unroll
  for (int m = 0; m < 4; ++m)
#pragma unroll
    for (int n = 0; n < 4; ++n)
#pragma unroll
      for (int i = 0; i < 4; ++i) {
        const unsigned short egu =
            (unsigned short)((eg_p[m][n][i >> 1] >> (16 * (i & 1))) & 0xFFFFu);
        const float xrf = b2f(f2b(acc[m][n][i]));          // xr bf16
        const unsigned short au = f2b(b2f(egu) * xrf);     // a = bf16(eg*xr)
        const int rloc = wr * 64 + m * 16 + (lane >> 4) * 4 + i;
        A[(size_t)(m0 + rloc) * NDIM + (size_t)(n0 + wc * 64 + n * 16 + (lane & 15))] = au;
      }
}

__global__ void k_scale(const float* __restrict__ es_part, const float* __restrict__ em_part,
                        float* __restrict__ scale2) {
  const int r = blockIdx.x * 256 + threadIdx.x;
  if (r >= MDIM) return;
  float s = 0.f, m = 0.f;
  for (int j = 0; j < 64; ++j) {
    s += es_part[(size_t)r * 64 + j];
    m = fmaxf(m, em_part[(size_t)r * 64 + j]);
  }
  scale2[2 * r] = b2f(f2b(1.0f / (s + 1e-8f)));  // inv_es (bf16 value)
  scale2[2 * r + 1] = b2f(f2b(tanhf(m)));        // gs (bf16 value)
}

// ---------- out GEMM: per-chunk bf16-rounded A @ W, scaled ----------

__global__ __launch_bounds__(256, 2) void k_out(const unsigned short* __restrict__ A,
                                                const unsigned short* __restrict__ wbT,
                                                const float* __restrict__ scale2,
                                                float* __restrict__ outp) {
  __shared__ unsigned short a_sm[128 * 64];
  __shared__ unsigned short b_sm[64 * 64];
  __shared__ float sc_sm[256];
  const int t = threadIdx.x;
  const int wave = t >> 6, lane = t & 63;
  const int wr = wave >> 1, wc = wave & 1;
  const int m0 = blockIdx.x * 128, d0 = blockIdx.y * 64;
  if (t < 128) {
    sc_sm[2 * t] = scale2[2 * (m0 + t)];
    sc_sm[2 * t + 1] = scale2[2 * (m0 + t) + 1];
  }
  const int arow = lane & 15;
  const int kcol = (lane >> 4) << 3;
  f32x4 cacc[4][2];
  float outv[4][2][4];
#pragma unroll
  for (int m = 0; m < 4; ++m)
#pragma unroll
    for (int n = 0; n < 2; ++n) {
      cacc[m][n] = (f32x4)0.0f;
#pragma unroll
      for (int i = 0; i < 4; ++i) outv[m][n][i] = 0.f;
    }
  for (int c = 0; c < 8; ++c) {
    for (int kk = 0; kk < 16; ++kk) {
      const int k0 = c * 1024 + kk * 64;
      stage_tile<128>(A, m0, k0, NDIM, a_sm, wave, lane);
      stage_tile<64>(wbT, d0, k0, NDIM, b_sm, wave, lane);
      asm volatile("s_waitcnt vmcnt(0)" ::: "memory");
      __syncthreads();
#pragma unroll
      for (int ks = 0; ks < 2; ++ks) {
        bf16x8 af[4], bfr[2];
#pragma unroll
        for (int m = 0; m < 4; ++m)
          af[m] = *(const bf16x8*)&a_sm[(wr * 64 + m * 16 + arow) * 64 + ks * 32 + kcol];
#pragma unroll
        for (int n = 0; n < 2; ++n)
          bfr[n] = *(const bf16x8*)&b_sm[(wc * 32 + n * 16 + arow) * 64 + ks * 32 + kcol];
#pragma unroll
        for (int m = 0; m < 4; ++m)
#pragma unroll
          for (int n = 0; n < 2; ++n)
            cacc[m][n] = __builtin_amdgcn_mfma_f32_16x16x32_bf16(af[m], bfr[n], cacc[m][n], 0, 0, 0);
      }
      __syncthreads();
    }
    // chunk boundary: round partial to bf16, accumulate f32 (mirrors .astype chain)
#pragma unroll
    for (int m = 0; m < 4; ++m)
#pragma unroll
      for (int n = 0; n < 2; ++n) {
#pragma unroll
        for (int i = 0; i < 4; ++i) outv[m][n][i] += b2f(f2b(cacc[m][n][i]));
        cacc[m][n] = (f32x4)0.0f;
      }
  }
#pragma unroll
  for (int m = 0; m < 4; ++m)
#pragma unroll
    for (int n = 0; n < 2; ++n)
#pragma unroll
      for (int i = 0; i < 4; ++i) {
        const int rloc = wr * 64 + m * 16 + (lane >> 4) * 4 + i;
        float v = outv[m][n][i] * sc_sm[2 * rloc];  // * inv_es
        v = v * sc_sm[2 * rloc + 1];                // * gs
        outp[(size_t)(m0 + rloc) * DDIM + (size_t)(d0 + wc * 32 + n * 16 + (lane & 15))] = v;
      }
}

extern "C" void kernel_launch(void* const* d_in, const int* in_sizes, int n_in,
                              void* d_out, int out_size, void* d_ws, size_t ws_size,
                              hipStream_t stream) {
  const float* x = (const float*)d_in[0];
  const float* h = (const float*)d_in[1];
  const float* emb = (const float*)d_in[2];
  const float* tau_off = (const float*)d_in[3];
  const float* w_read = (const float*)d_in[4];
  const float* w_write = (const float*)d_in[5];

  char* ws = (char*)d_ws;
  const size_t MB = 1024 * 1024;
  unsigned short* eb = (unsigned short*)(ws);             // 16 MB
  unsigned short* rb = (unsigned short*)(ws + 16 * MB);   // 16 MB
  unsigned short* wbT = (unsigned short*)(ws + 32 * MB);  // 16 MB
  unsigned short* hb = (unsigned short*)(ws + 48 * MB);   // 4 MB
  unsigned short* xb = (unsigned short*)(ws + 52 * MB);   // 4 MB
  unsigned short* A = (unsigned short*)(ws + 56 * MB);    // 32 MB
  float* tau = (float*)(ws + 88 * MB);
  float* stat_s = (float*)(ws + 88 * MB + 1 * 65536);
  float* stat_q = (float*)(ws + 88 * MB + 2 * 65536);
  float* es_part = (float*)(ws + 88 * MB + 3 * 65536);   // 512 KB
  float* em_part = (float*)(ws + 88 * MB + 11 * 65536);  // 512 KB
  float* scale2 = (float*)(ws + 88 * MB + 19 * 65536);   // 16 KB
  if (ws_size < 88 * MB + 20 * 65536) return;  // insufficient workspace guard
  float* outp = (float*)d_out;

  k_norm<<<NDIM, 256, 0, stream>>>(emb, eb);
  k_cast<<<(NDIM * DDIM / 4) / 256, 256, 0, stream>>>(w_read, rb, NDIM * DDIM / 4);
  k_cast<<<(MDIM * DDIM / 4) / 256, 256, 0, stream>>>(h, hb, MDIM * DDIM / 4);
  k_cast<<<(MDIM * DDIM / 4) / 256, 256, 0, stream>>>(x, xb, MDIM * DDIM / 4);
  k_twt<<<dim3(NDIM / 64, DDIM / 64), 256, 0, stream>>>(w_write, wbT);
  k_stats<<<dim3(MDIM / 128, 8), 256, 0, stream>>>(hb, eb, stat_s, stat_q);
  k_tau<<<MDIM / 256, 256, 0, stream>>>(stat_s, stat_q, tau_off, tau);
  k_gates<<<dim3(MDIM / 128, NDIM / 128), 256, 0, stream>>>(hb, eb, xb, rb, tau, A,
                                                            es_part, em_part);
  k_scale<<<MDIM / 256, 256, 0, stream>>>(es_part, em_part, scale2);
  k_out<<<dim3(MDIM / 128, DDIM / 64), 256, 0, stream>>>(A, wbT, scale2, outp);
}

// Round 2
// 211.956 us; speedup vs baseline: 1.4604x; 1.4604x over previous
//
#include <hip/hip_runtime.h>

// DAWN_14886356647950: fused gated sparse read-write (B=2,S=1024,D=1024,N=8192,NC=8)
// R1: 256x256 8-phase GEMM template (T2 swizzle + T3/T4 counted vmcnt + T5 setprio)
// for the three big GEMMs (sc, xr, out). Chunk-split k_out writes bf16-rounded
// per-chunk partials (deterministic), k_finish reduces+scales.

#define MDIM 2048
#define DDIM 1024
#define NDIM 8192

typedef __attribute__((ext_vector_type(8))) __bf16 bf16x8;
typedef __attribute__((ext_vector_type(4))) float f32x4;

static __device__ __forceinline__ unsigned short f2b(float f) {
  unsigned u = __float_as_uint(f);
  u = (u + 0x7FFFu + ((u >> 16) & 1u)) >> 16;  // RTNE
  return (unsigned short)u;
}
static __device__ __forceinline__ float b2f(unsigned short s) {
  return __uint_as_float(((unsigned)s) << 16);
}

// ==================== 256x256 8-phase GEMM core ====================
// 512 threads = 8 waves (2M x 4N). Per-wave 128x64 output. BK=64, NT=16 tiles.
// LDS 128KB: buf(2) x {A(2 halves),B(2 halves)} x 16KB. st-swizzle: byte ^= (row&7)<<4.

// Stage one 128x64 half-tile. LDS dest linear (wave-uniform base + lane*16B);
// swizzle applied by permuting the per-lane GLOBAL source column (involution).
static __device__ __forceinline__ void stage_half(const unsigned short* __restrict__ src,
                                                  int ld, int row0, int k0,
                                                  char* lds, int lds_off, int w, int l) {
  const int rsub = l >> 3;
  const int col = k0 + 8 * ((l & 7) ^ rsub);
#pragma unroll
  for (int j = 0; j < 2; ++j) {
    const unsigned short* g =
        src + (size_t)(row0 + w * 8 + j * 64 + rsub) * (size_t)ld + col;
    __builtin_amdgcn_global_load_lds(
        (const __attribute__((address_space(1))) unsigned int*)(const void*)g,
        (__attribute__((address_space(3))) unsigned int*)(void*)(lds + lds_off + j * 8192 + w * 1024),
        16, 0, 0);
  }
}

#define LDSF(off) (*(const bf16x8*)(lds + (off)))
#define MFMA_BF16 __builtin_amdgcn_mfma_f32_16x16x32_bf16

static __device__ __forceinline__ void gemm256(const unsigned short* __restrict__ asrc,
                                               const unsigned short* __restrict__ bsrc,
                                               int ld, int m0, int n0, int kbase,
                                               char* lds, f32x4 (&acc)[8][4],
                                               int w, int l, int wr, int wc) {
  const int lrow = l & 15, lk = l >> 4;
  const int axor = (l & 7) << 4;
  const int kx0 = (lk << 4) ^ axor;        // ks=0 swizzled k-byte
  const int kx1 = (64 | (lk << 4)) ^ axor; // ks=1
  const int arow_off = lrow * 128;
  const int brow_off = ((wc & 1) * 64 + lrow) * 128;

  // Prologue: A0(0) A1(0) B0(0) B1(0) B0(1) B1(1); drain tile0 (vmcnt(4) keeps B(1) in flight)
  stage_half(asrc, ld, m0,       kbase,      lds, 0,             w, l);
  stage_half(asrc, ld, m0 + 128, kbase,      lds, 16384,         w, l);
  stage_half(bsrc, ld, n0,       kbase,      lds, 32768,         w, l);
  stage_half(bsrc, ld, n0 + 128, kbase,      lds, 49152,         w, l);
  stage_half(bsrc, ld, n0,       kbase + 64, lds, 65536 + 32768, w, l);
  stage_half(bsrc, ld, n0 + 128, kbase + 64, lds, 65536 + 49152, w, l);
  asm volatile("s_waitcnt vmcnt(4)" ::: "memory");
  __builtin_amdgcn_s_barrier();

  bf16x8 a[4][2], blo[2][2], bhi[2][2];
#pragma unroll 2
  for (int s = 0; s < 16; ++s) {
    const int ab = (s & 1) * 65536 + wr * 16384;
    const int bb = (s & 1) * 65536 + 32768 + (wc >> 1) * 16384;
    // ---- phase q0: read A-lo + B-lo; stage A0(s+1); MFMA (m-lo x n-lo)
#pragma unroll
    for (int m = 0; m < 4; ++m) {
      a[m][0] = LDSF(ab + arow_off + m * 2048 + kx0);
      a[m][1] = LDSF(ab + arow_off + m * 2048 + kx1);
    }
#pragma unroll
    for (int n = 0; n < 2; ++n) {
      blo[n][0] = LDSF(bb + brow_off + n * 2048 + kx0);
      blo[n][1] = LDSF(bb + brow_off + n * 2048 + kx1);
    }
    if (s + 1 < 16)
      stage_half(asrc, ld, m0, kbase + (s + 1) * 64, lds, ((s + 1) & 1) * 65536, w, l);
    asm volatile("s_waitcnt lgkmcnt(8)" ::: "memory");
    __builtin_amdgcn_s_barrier();
    asm volatile("s_waitcnt lgkmcnt(0)" ::: "memory");
    __builtin_amdgcn_s_setprio(1);
#pragma unroll
    for (int ks = 0; ks < 2; ++ks)
#pragma unroll
      for (int n = 0; n < 2; ++n)
#pragma unroll
        for (int m = 0; m < 4; ++m)
          acc[m][n] = MFMA_BF16(a[m][ks], blo[n][ks], acc[m][n], 0, 0, 0);
    __builtin_amdgcn_s_setprio(0);
    __builtin_amdgcn_s_barrier();
    // ---- phase q1: read B-hi; stage A1(s+1); MFMA (m-lo x n-hi)
#pragma unroll
    for (int n = 0; n < 2; ++n) {
      bhi[n][0] = LDSF(bb + brow_off + (n + 2) * 2048 + kx0);
      bhi[n][1] = LDSF(bb + brow_off + (n + 2) * 2048 + kx1);
    }
    if (s + 1 < 16)
      stage_half(asrc, ld, m0 + 128, kbase + (s + 1) * 64, lds,
                 ((s + 1) & 1) * 65536 + 16384, w, l);
    __builtin_amdgcn_s_barrier();
    asm volatile("s_waitcnt lgkmcnt(0)" ::: "memory");
    __builtin_amdgcn_s_setprio(1);
#pragma unroll
    for (int ks = 0; ks < 2; ++ks)
#pragma unroll
      for (int n = 0; n < 2; ++n)
#pragma unroll
        for (int m = 0; m < 4; ++m)
          acc[m][n + 2] = MFMA_BF16(a[m][ks], bhi[n][ks], acc[m][n + 2], 0, 0, 0);
    __builtin_amdgcn_s_setprio(0);
    __builtin_amdgcn_s_barrier();
    // ---- phase q2: read A-hi (overwrite a); stage B0(s+2); MFMA (m-hi x n-hi)
#pragma unroll
    for (int m = 0; m < 4; ++m) {
      a[m][0] = LDSF(ab + arow_off + (m + 4) * 2048 + kx0);
      a[m][1] = LDSF(ab + arow_off + (m + 4) * 2048 + kx1);
    }
    if (s + 2 < 16)
      stage_half(bsrc, ld, n0, kbase + (s + 2) * 64, lds, (s & 1) * 65536 + 32768, w, l);
    __builtin_amdgcn_s_barrier();
    asm volatile("s_waitcnt lgkmcnt(0)" ::: "memory");
    __builtin_amdgcn_s_setprio(1);
#pragma unroll
    for (int ks = 0; ks < 2; ++ks)
#pragma unroll
      for (int n = 0; n < 2; ++n)
#pragma unroll
        for (int m = 0; m < 4; ++m)
          acc[m + 4][n + 2] = MFMA_BF16(a[m][ks], bhi[n][ks], acc[m + 4][n + 2], 0, 0, 0);
    __builtin_amdgcn_s_setprio(0);
    __builtin_amdgcn_s_barrier();
    // ---- phase q3: stage B1(s+2); MFMA (m-hi x n-lo); tile-boundary vmcnt
    if (s + 2 < 16)
      stage_half(bsrc, ld, n0 + 128, kbase + (s + 2) * 64, lds, (s & 1) * 65536 + 49152, w, l);
    __builtin_amdgcn_s_barrier();
    asm volatile("s_waitcnt lgkmcnt(0)" ::: "memory");
    __builtin_amdgcn_s_setprio(1);
#pragma unroll
    for (int ks = 0; ks < 2; ++ks)
#pragma unroll
      for (int n = 0; n < 2; ++n)
#pragma unroll
        for (int m = 0; m < 4; ++m)
          acc[m + 4][n] = MFMA_BF16(a[m][ks], blo[n][ks], acc[m + 4][n], 0, 0, 0);
    __builtin_amdgcn_s_setprio(0);
    if (s <= 13) {
      asm volatile("s_waitcnt vmcnt(4)" ::: "memory");  // tile s+1 halves complete
    } else if (s == 14) {
      asm volatile("s_waitcnt vmcnt(0)" ::: "memory");  // last tile fully staged
    }
    __builtin_amdgcn_s_barrier();
  }
}

// ==================== prep kernels ====================

__global__ __launch_bounds__(256) void k_norm(const float* __restrict__ emb,
                                              unsigned short* __restrict__ eb) {
  const int n = blockIdx.x, t = threadIdx.x;
  const float4 v = ((const float4*)(emb + (size_t)n * 1024))[t];
  float ss = v.x * v.x + v.y * v.y + v.z * v.z + v.w * v.w;
#pragma unroll
  for (int off = 1; off < 64; off <<= 1) ss += __shfl_xor(ss, off, 64);
  __shared__ float wsum[4];
  if ((t & 63) == 0) wsum[t >> 6] = ss;
  __syncthreads();
  const float tot = wsum[0] + wsum[1] + wsum[2] + wsum[3];
  const float denom = sqrtf(tot) + 1e-8f;
  ushort4 o;
  o.x = f2b(v.x / denom);
  o.y = f2b(v.y / denom);
  o.z = f2b(v.z / denom);
  o.w = f2b(v.w / denom);
  ((ushort4*)(eb + (size_t)n * 1024))[t] = o;
}

__global__ __launch_bounds__(256) void k_cast(const float* __restrict__ in,
                                              unsigned short* __restrict__ out, int n4) {
  const int i = blockIdx.x * 256 + threadIdx.x;
  if (i >= n4) return;
  const float4 v = ((const float4*)in)[i];
  ushort4 o;
  o.x = f2b(v.x);
  o.y = f2b(v.y);
  o.z = f2b(v.z);
  o.w = f2b(v.w);
  ((ushort4*)out)[i] = o;
}

// w_write [N][D] f32 -> wbT [D][N] bf16
__global__ __launch_bounds__(256) void k_twt(const float* __restrict__ w,
                                             unsigned short* __restrict__ wbT) {
  __shared__ float tsm[64][65];
  const int nb = blockIdx.x, db = blockIdx.y, t = threadIdx.x;
  const int r = t >> 2, c4 = (t & 3) * 16;
#pragma unroll
  for (int j = 0; j < 4; ++j) {
    const float4 v = *(const float4*)&w[(size_t)(nb * 64 + r) * 1024 + db * 64 + c4 + 4 * j];
    tsm[r][c4 + 4 * j + 0] = v.x;
    tsm[r][c4 + 4 * j + 1] = v.y;
    tsm[r][c4 + 4 * j + 2] = v.z;
    tsm[r][c4 + 4 * j + 3] = v.w;
  }
  __syncthreads();
  const int dr = t >> 2, nc0 = (t & 3) * 16;
  unsigned pk[8];
#pragma unroll
  for (int j = 0; j < 8; ++j) {
    const unsigned lo = f2b(tsm[nc0 + 2 * j][dr]);
    const unsigned hi = f2b(tsm[nc0 + 2 * j + 1][dr]);
    pk[j] = lo | (hi << 16);
  }
  uint4* dst = (uint4*)(wbT + (size_t)(db * 64 + dr) * 8192 + nb * 64 + nc0);
  uint4 w0, w1;
  w0.x = pk[0]; w0.y = pk[1]; w0.z = pk[2]; w0.w = pk[3];
  w1.x = pk[4]; w1.y = pk[5]; w1.z = pk[6]; w1.w = pk[7];
  dst[0] = w0;
  dst[1] = w1;
}

// ==================== stats (old 128^2 path, small) ====================

template <int TROWS>
static __device__ __forceinline__ void stage_tile(const unsigned short* __restrict__ src,
                                                  int row0, int k0, int ld,
                                                  unsigned short* lds, int wave, int lane) {
  const int rsub = lane >> 3;
  const int csub = (lane & 7) << 3;
#pragma unroll
  for (int q = 0; q < TROWS / 32; ++q) {
    const int p = q * 4 + wave;
    const unsigned short* g =
        src + (size_t)(row0 + p * 8 + rsub) * (size_t)ld + (size_t)(k0 + csub);
    __builtin_amdgcn_global_load_lds(
        (const __attribute__((address_space(1))) unsigned int*)(const void*)g,
        (__attribute__((address_space(3))) unsigned int*)(void*)(lds + p * 512),
        16, 0, 0);
  }
}

static __device__ __forceinline__ void gemm_128_128(const unsigned short* __restrict__ asrc,
                                                    const unsigned short* __restrict__ bsrc,
                                                    int m0, int n0, int K, int lda, int ldb,
                                                    unsigned short* a_sm, unsigned short* b_sm,
                                                    f32x4 (&acc)[4][4], int wave, int lane,
                                                    int wr, int wc) {
  const int arow = lane & 15;
  const int kcol = (lane >> 4) << 3;
  for (int k0 = 0; k0 < K; k0 += 64) {
    stage_tile<128>(asrc, m0, k0, lda, a_sm, wave, lane);
    stage_tile<128>(bsrc, n0, k0, ldb, b_sm, wave, lane);
    asm volatile("s_waitcnt vmcnt(0)" ::: "memory");
    __syncthreads();
#pragma unroll
    for (int ks = 0; ks < 2; ++ks) {
      bf16x8 af[4], bfr[4];
#pragma unroll
      for (int m = 0; m < 4; ++m)
        af[m] = *(const bf16x8*)&a_sm[(wr * 64 + m * 16 + arow) * 64 + ks * 32 + kcol];
#pragma unroll
      for (int n = 0; n < 4; ++n)
        bfr[n] = *(const bf16x8*)&b_sm[(wc * 64 + n * 16 + arow) * 64 + ks * 32 + kcol];
#pragma unroll
      for (int m = 0; m < 4; ++m)
#pragma unroll
        for (int n = 0; n < 4; ++n)
          acc[m][n] = MFMA_BF16(af[m], bfr[n], acc[m][n], 0, 0, 0);
    }
    __syncthreads();
  }
}

__global__ __launch_bounds__(256, 2) void k_stats(const unsigned short* __restrict__ hb,
                                                  const unsigned short* __restrict__ eb,
                                                  float* __restrict__ stat_s,
                                                  float* __restrict__ stat_q) {
  __shared__ unsigned short a_sm[128 * 64];
  __shared__ unsigned short b_sm[128 * 64];
  __shared__ float red_s[2][128];
  __shared__ float red_q[2][128];
  const int t = threadIdx.x;
  const int wave = t >> 6, lane = t & 63;
  const int wr = wave >> 1, wc = wave & 1;
  const int m0 = blockIdx.x * 128, n0 = blockIdx.y * 128;
  f32x4 acc[4][4];
#pragma unroll
  for (int m = 0; m < 4; ++m)
#pragma unroll
    for (int n = 0; n < 4; ++n) acc[m][n] = (f32x4)0.0f;
  gemm_128_128(hb, eb, m0, n0, 1024, 1024, 1024, a_sm, b_sm, acc, wave, lane, wr, wc);

  float s_r[4][4], q_r[4][4];
#pragma unroll
  for (int m = 0; m < 4; ++m)
#pragma unroll
    for (int i = 0; i < 4; ++i) { s_r[m][i] = 0.f; q_r[m][i] = 0.f; }
#pragma unroll
  for (int m = 0; m < 4; ++m)
#pragma unroll
    for (int n = 0; n < 4; ++n)
#pragma unroll
      for (int i = 0; i < 4; ++i) {
        const float scf = b2f(f2b(acc[m][n][i]));
        s_r[m][i] += scf;
        q_r[m][i] += b2f(f2b(scf * scf));
      }
#pragma unroll
  for (int m = 0; m < 4; ++m)
#pragma unroll
    for (int i = 0; i < 4; ++i) {
      float s = s_r[m][i], q = q_r[m][i];
      for (int off = 1; off < 16; off <<= 1) {
        s += __shfl_xor(s, off, 64);
        q += __shfl_xor(q, off, 64);
      }
      if ((lane & 15) == 0) {
        const int rloc = wr * 64 + m * 16 + (lane >> 4) * 4 + i;
        red_s[wc][rloc] = s;
        red_q[wc][rloc] = q;
      }
    }
  __syncthreads();
  if (t < 128) {
    stat_s[(size_t)(m0 + t) * 8 + blockIdx.y] = red_s[0][t] + red_s[1][t];
    stat_q[(size_t)(m0 + t) * 8 + blockIdx.y] = red_q[0][t] + red_q[1][t];
  }
}

__global__ void k_tau(const float* __restrict__ stat_s, const float* __restrict__ stat_q,
                      const float* __restrict__ tau_off, float* __restrict__ tau) {
  const int r = blockIdx.x * 256 + threadIdx.x;
  if (r >= MDIM) return;
  float S = 0.f, Q = 0.f;
#pragma unroll
  for (int j = 0; j < 8; ++j) {
    S += stat_s[(size_t)r * 8 + j];
    Q += stat_q[(size_t)r * 8 + j];
  }
  const float s_sum = S * 8.0f;
  const float sq_sum = Q * 8.0f;
  const float mean = s_sum * (1.0f / 8192.0f);
  const float var = __fsub_rn(sq_sum * (1.0f / 8192.0f), __fmul_rn(mean, mean));
  const float sd = __fadd_rn(__fsqrt_rn(var), 1e-8f);
  const float tv = __fadd_rn(mean, __fmul_rn(tau_off[r], sd));
  tau[r] = b2f(f2b(tv));
}

// ==================== k_sc: sc GEMM + gating -> eg, es/em partials ====================

__global__ __launch_bounds__(512, 2) void k_sc(const unsigned short* __restrict__ hb,
                                               const unsigned short* __restrict__ eb,
                                               const float* __restrict__ tau,
                                               unsigned short* __restrict__ Aeg,
                                               float* __restrict__ es_part,
                                               float* __restrict__ em_part) {
  __shared__ __align__(16) char lds[131072];
  const int t = threadIdx.x, w = t >> 6, l = t & 63;
  const int wr = w >> 2, wc = w & 3;
  const int bid = blockIdx.x;
  const int swz = (bid & 7) * 32 + (bid >> 3);
  const int m0 = (swz >> 5) * 256, n0 = (swz & 31) * 256;
  f32x4 acc[8][4];
#pragma unroll
  for (int m = 0; m < 8; ++m)
#pragma unroll
    for (int n = 0; n < 4; ++n) acc[m][n] = (f32x4)0.0f;
  gemm256(hb, eb, 1024, m0, n0, 0, lds, acc, w, l, wr, wc);

  __syncthreads();
  float* tau_sm = (float*)lds;
  float* red_es = (float*)(lds + 1024);
  float* red_em = (float*)(lds + 1024 + 4096);
  if (t < 256) tau_sm[t] = tau[m0 + t];
  __syncthreads();
  const int lrow = l & 15, lk = l >> 4;
#pragma unroll
  for (int m = 0; m < 8; ++m) {
#pragma unroll
    for (int i = 0; i < 4; ++i) {
      const int rl = wr * 128 + m * 16 + lk * 4 + i;
      const float taub = tau_sm[rl];
      float es_v = 0.f, em_v = 0.f;
#pragma unroll
      for (int n = 0; n < 4; ++n) {
        const float scf = b2f(f2b(acc[m][n][i]));
        const float rawf = b2f(f2b(scf - taub));
        float gcf;
        if (rawf > 0.f) gcf = fminf(rawf, 10.0f);
        else gcf = b2f(f2b(1e-6f * expf(fmaxf(rawf, -10.0f))));
        const unsigned short egu = f2b(expf(gcf) - 1.0f);
        const float ef = b2f(egu);
        es_v += ef;
        em_v = fmaxf(em_v, ef);
        Aeg[(size_t)(m0 + rl) * NDIM + (size_t)(n0 + wc * 64 + n * 16 + lrow)] = egu;
      }
      for (int off = 1; off < 16; off <<= 1) {
        es_v += __shfl_xor(es_v, off, 64);
        em_v = fmaxf(em_v, __shfl_xor(em_v, off, 64));
      }
      if (lrow == 0) {
        red_es[wc * 256 + rl] = es_v;
        red_em[wc * 256 + rl] = em_v;
      }
    }
  }
  __syncthreads();
  if (t < 256) {
    const float s = red_es[t] + red_es[256 + t] + red_es[512 + t] + red_es[768 + t];
    const float e = fmaxf(fmaxf(red_em[t], red_em[256 + t]),
                          fmaxf(red_em[512 + t], red_em[768 + t]));
    es_part[(size_t)(m0 + t) * 32 + (n0 >> 8)] = s;
    em_part[(size_t)(m0 + t) * 32 + (n0 >> 8)] = e;
  }
}

// ==================== k_xr: xr GEMM, A = bf16(eg * xr) in place ====================

__global__ __launch_bounds__(512, 2) void k_xr(const unsigned short* __restrict__ xb,
                                               const unsigned short* __restrict__ rb,
                                               unsigned short* __restrict__ Aeg) {
  __shared__ __align__(16) char lds[131072];
  const int t = threadIdx.x, w = t >> 6, l = t & 63;
  const int wr = w >> 2, wc = w & 3;
  const int bid = blockIdx.x;
  const int swz = (bid & 7) * 32 + (bid >> 3);
  const int m0 = (swz >> 5) * 256, n0 = (swz & 31) * 256;
  f32x4 acc[8][4];
#pragma unroll
  for (int m = 0; m < 8; ++m)
#pragma unroll
    for (int n = 0; n < 4; ++n) acc[m][n] = (f32x4)0.0f;
  gemm256(xb, rb, 1024, m0, n0, 0, lds, acc, w, l, wr, wc);

  const int lrow = l & 15, lk = l >> 4;
#pragma unroll
  for (int m = 0; m < 8; ++m)
#pragma unroll
    for (int n = 0; n < 4; ++n)
#pragma unroll
      for (int i = 0; i < 4; ++i) {
        const int rl = wr * 128 + m * 16 + lk * 4 + i;
        const size_t idx =
            (size_t)(m0 + rl) * NDIM + (size_t)(n0 + wc * 64 + n * 16 + lrow);
        const unsigned short egu = Aeg[idx];
        const float xrf = b2f(f2b(acc[m][n][i]));
        Aeg[idx] = f2b(b2f(egu) * xrf);
      }
}

// ==================== k_out: per-chunk GEMM -> bf16 partial ====================

__global__ __launch_bounds__(512, 2) void k_out(const unsigned short* __restrict__ A,
                                                const unsigned short* __restrict__ wbT,
                                                unsigned short* __restrict__ pacc) {
  __shared__ __align__(16) char lds[131072];
  const int t = threadIdx.x, w = t >> 6, l = t & 63;
  const int wr = w >> 2, wc = w & 3;
  const int bid = blockIdx.x;
  const int swz = (bid & 7) * 32 + (bid >> 3);
  const int bm = swz >> 5, chunk = (swz >> 2) & 7, bd = swz & 3;
  const int m0 = bm * 256, d0 = bd * 256;
  f32x4 acc[8][4];
#pragma unroll
  for (int m = 0; m < 8; ++m)
#pragma unroll
    for (int n = 0; n < 4; ++n) acc[m][n] = (f32x4)0.0f;
  gemm256(A, wbT, 8192, m0, d0, chunk * 1024, lds, acc, w, l, wr, wc);

  const int lrow = l & 15, lk = l >> 4;
#pragma unroll
  for (int m = 0; m < 8; ++m)
#pragma unroll
    for (int n = 0; n < 4; ++n)
#pragma unroll
      for (int i = 0; i < 4; ++i) {
        const int rl = wr * 128 + m * 16 + lk * 4 + i;
        pacc[((size_t)chunk * MDIM + (m0 + rl)) * DDIM +
             (size_t)(d0 + wc * 64 + n * 16 + lrow)] = f2b(acc[m][n][i]);
      }
}

// ==================== scales + finish ====================

__global__ void k_scale(const float* __restrict__ es_part, const float* __restrict__ em_part,
                        float* __restrict__ scale2) {
  const int r = blockIdx.x * 256 + threadIdx.x;
  if (r >= MDIM) return;
  float s = 0.f, m = 0.f;
#pragma unroll
  for (int j = 0; j < 32; ++j) {
    s += es_part[(size_t)r * 32 + j];
    m = fmaxf(m, em_part[(size_t)r * 32 + j]);
  }
  scale2[2 * r] = b2f(f2b(1.0f / (s + 1e-8f)));  // inv_es (bf16 value)
  scale2[2 * r + 1] = b2f(f2b(tanhf(m)));        // gs (bf16 value)
}

__global__ __launch_bounds__(256) void k_finish(const unsigned short* __restrict__ pacc,
                                                const float* __restrict__ scale2,
                                                float* __restrict__ outp) {
  const int t = blockIdx.x * 256 + threadIdx.x;  // 512K threads
  const int r = t >> 8;
  const int d4 = (t & 255) * 4;
  float sx = 0.f, sy = 0.f, sz = 0.f, sw = 0.f;
#pragma unroll
  for (int c = 0; c < 8; ++c) {
    const ushort4 v = *(const ushort4*)(pacc + ((size_t)c * MDIM + r) * DDIM + d4);
    sx += b2f(v.x);
    sy += b2f(v.y);
    sz += b2f(v.z);
    sw += b2f(v.w);
  }
  const float inv = scale2[2 * r];
  const float gsv = scale2[2 * r + 1];
  float4 o;
  o.x = (sx * inv) * gsv;
  o.y = (sy * inv) * gsv;
  o.z = (sz * inv) * gsv;
  o.w = (sw * inv) * gsv;
  *(float4*)(outp + (size_t)r * DDIM + d4) = o;
}

// ==================== launch ====================

extern "C" void kernel_launch(void* const* d_in, const int* in_sizes, int n_in,
                              void* d_out, int out_size, void* d_ws, size_t ws_size,
                              hipStream_t stream) {
  const float* x = (const float*)d_in[0];
  const float* h = (const float*)d_in[1];
  const float* emb = (const float*)d_in[2];
  const float* tau_off = (const float*)d_in[3];
  const float* w_read = (const float*)d_in[4];
  const float* w_write = (const float*)d_in[5];

  char* ws = (char*)d_ws;
  const size_t MB = 1024 * 1024;
  // Layout (lifetimes): rb[prep->xr], eb[prep->sc], wbT[prep->out], hb, xb,
  // Aeg[sc->xr->out], pacc overlays rb+eb [out->finish]
  unsigned short* rb = (unsigned short*)(ws);             // 16 MB
  unsigned short* eb = (unsigned short*)(ws + 16 * MB);   // 16 MB
  unsigned short* wbT = (unsigned short*)(ws + 32 * MB);  // 16 MB
  unsigned short* hb = (unsigned short*)(ws + 48 * MB);   // 4 MB
  unsigned short* xb = (unsigned short*)(ws + 52 * MB);   // 4 MB
  unsigned short* Aeg = (unsigned short*)(ws + 56 * MB);  // 32 MB
  unsigned short* pacc = (unsigned short*)(ws);           // 32 MB overlay (rb+eb dead)
  float* tau = (float*)(ws + 88 * MB);                    // 8 KB
  float* stat_s = (float*)(ws + 88 * MB + 1 * 65536);
  float* stat_q = (float*)(ws + 88 * MB + 2 * 65536);
  float* es_part = (float*)(ws + 88 * MB + 3 * 65536);    // 256 KB
  float* em_part = (float*)(ws + 88 * MB + 7 * 65536);    // 256 KB
  float* scale2 = (float*)(ws + 88 * MB + 11 * 65536);    // 16 KB
  if (ws_size < 88 * MB + 12 * 65536) return;
  float* outp = (float*)d_out;

  k_norm<<<NDIM, 256, 0, stream>>>(emb, eb);
  k_cast<<<(NDIM * DDIM / 4) / 256, 256, 0, stream>>>(w_read, rb, NDIM * DDIM / 4);
  k_cast<<<(MDIM * DDIM / 4) / 256, 256, 0, stream>>>(h, hb, MDIM * DDIM / 4);
  k_cast<<<(MDIM * DDIM / 4) / 256, 256, 0, stream>>>(x, xb, MDIM * DDIM / 4);
  k_twt<<<dim3(NDIM / 64, DDIM / 64), 256, 0, stream>>>(w_write, wbT);
  k_stats<<<dim3(MDIM / 128, 8), 256, 0, stream>>>(hb, eb, stat_s, stat_q);
  k_tau<<<MDIM / 256, 256, 0, stream>>>(stat_s, stat_q, tau_off, tau);
  k_sc<<<256, 512, 0, stream>>>(hb, eb, tau, Aeg, es_part, em_part);
  k_scale<<<MDIM / 256, 256, 0, stream>>>(es_part, em_part, scale2);
  k_xr<<<256, 512, 0, stream>>>(xb, rb, Aeg);
  k_out<<<256, 512, 0, stream>>>(Aeg, wbT, pacc);
  k_finish<<<(MDIM * DDIM / 4) / 256, 256, 0, stream>>>(pacc, scale2, outp);
}